// Round 1
// 102.466 us; speedup vs baseline: 2.8160x; 2.8160x over previous
//
#include <hip/hip_runtime.h>
#include <hip/hip_bf16.h>

// ---------------------------------------------------------------------------
// Fused SiamCAR head, one block per batch (B=512, 256 threads).
// Round 3: pointwise conv and 3x3 pred conv moved to MFMA (bf16 in / fp32 acc).
//  - depthwise output stored transposed d_T[pix][p] (B-operand, k-contiguous)
//  - pointwise:  feat[32oc x 256pix] = pw(32x64) x d(64x256) via 16 MFMA/wave
//  - pred conv:  implicit GEMM, M=16 (rows<NOUT live), K = tau*32+ocl,
//                accumulated across oc-chunks directly in MFMA acc regs
//    -> pacc[NOUT][16] + shfl reduction + wbuf eliminated (spill fix)
// corr GEMM / attention MLP / depthwise stay fp32 VALU (accuracy-safe).
// ---------------------------------------------------------------------------

typedef __attribute__((ext_vector_type(8))) short  bf16x8;
typedef __attribute__((ext_vector_type(4))) float  f32x4;

union U8 { bf16x8 v; uint4 q; unsigned short u[8]; };

__device__ __forceinline__ float bf2f(unsigned short h){
  union { unsigned int u; float f; } c; c.u = ((unsigned int)h) << 16; return c.f;
}
__device__ __forceinline__ unsigned short f2bf(float f){
  union { float f; unsigned int u; } c; c.f = f;
  unsigned int r = (c.u + 0x7FFFu + ((c.u >> 16) & 1u)) >> 16;  // RNE
  return (unsigned short)r;
}
__device__ __forceinline__ unsigned int f2bf2(float lo, float hi){
  return (unsigned int)f2bf(lo) | ((unsigned int)f2bf(hi) << 16);
}

// corr A tile [64][256] bf16, 16B-chunk XOR swizzle (unchanged, verified).
__device__ __forceinline__ int swz(int row, int pix){
  return row*256 + (((pix>>3) ^ (row&31))<<3) + (pix&7);
}
// d_T [256 pix][64 p] bf16, byte offset. 8-elem (16B) k-chunks XOR'd by pix.
__device__ __forceinline__ int dT_off(int pix, int p){
  return (pix<<7) + (((((p>>3) ^ pix) & 7)) << 4) + ((p & 7) << 1);
}
// feat_T [256 pix][32 ocl] bf16, byte offset. 2-bit chunk XOR by pix and pix>>2.
__device__ __forceinline__ int fT_off(int pix, int ocl){
  return (pix<<6) + ((((ocl>>3) ^ pix ^ (pix>>2)) & 3) << 4) + ((ocl & 7) << 1);
}
// pw A-tile [32 ocl][64 p] bf16, byte offset.
__device__ __forceinline__ int pA_off(int ocl, int p){
  return (ocl<<7) + (((((p>>3) ^ ocl) & 7)) << 4) + ((p & 7) << 1);
}

// load one 16-pixel row (bf16, swizzled corr A) -> fp32, zero-padded
__device__ __forceinline__ void load_row16(const unsigned short* s, int p, int r,
                                           float* out){
  if (r >= 0 && r < 16){
    unsigned short tr[16];
    *(uint4*)&tr[0] = *(uint4*)&s[swz(p, r*16)];
    *(uint4*)&tr[8] = *(uint4*)&s[swz(p, r*16 + 8)];
    #pragma unroll
    for (int j=0;j<16;++j) out[j] = bf2f(tr[j]);
  } else {
    #pragma unroll
    for (int j=0;j<16;++j) out[j] = 0.f;
  }
}

// stage one 32-oc chunk of pw (fp32 global) -> [32][64] bf16 swizzled LDS
__device__ __forceinline__ void stage_pw(int tid, int oc0,
                                         const float* __restrict__ pw,
                                         unsigned char* __restrict__ dst){
  const int ocl = tid >> 3, p0 = (tid & 7) << 3;
  const float4 f0 = *(const float4*)&pw[(oc0 + ocl)*64 + p0];
  const float4 f1 = *(const float4*)&pw[(oc0 + ocl)*64 + p0 + 4];
  U8 w;
  w.u[0]=f2bf(f0.x); w.u[1]=f2bf(f0.y); w.u[2]=f2bf(f0.z); w.u[3]=f2bf(f0.w);
  w.u[4]=f2bf(f1.x); w.u[5]=f2bf(f1.y); w.u[6]=f2bf(f1.z); w.u[7]=f2bf(f1.w);
  *(uint4*)(dst + pA_off(ocl, p0)) = w.q;
}

// stage pred weights for one oc-chunk: wA[o][k = tau*32 + ocl] bf16, linear
template<int NOUT>
__device__ __forceinline__ void stage_wA(int tid, int oc0,
                                         const float* __restrict__ pdw,
                                         unsigned char* __restrict__ dst){
  #pragma unroll
  for (int i=0;i<(NOUT*288+255)/256;++i){
    const int idx = i*256 + tid;
    if (idx < NOUT*288){
      const int o   = idx / 288;
      const int rem = idx - o*288;
      const int tau = rem >> 5, ocl = rem & 31;
      *(unsigned short*)(dst + (idx<<1)) =
          f2bf(pdw[(o*256 + oc0 + ocl)*9 + tau]);
    }
  }
}

template<int NOUT>
__device__ __forceinline__ void run_tower(
    int tid, const unsigned int pk[8][4],
    const float* __restrict__ dw,  const float* __restrict__ pw,
    const float* __restrict__ bng, const float* __restrict__ bnb,
    const float* __restrict__ bnm, const float* __restrict__ bnv,
    const float* __restrict__ pdw, const float* __restrict__ pdb,
    float* __restrict__ outp, float adj, const float* __restrict__ biasp,
    unsigned char* smemA, unsigned char* smemB)
{
  const int lane = tid & 63, wave = tid >> 6;
  const int l15 = lane & 15, lg = lane >> 4;   // 16-lane group structure
  unsigned short* sA16 = (unsigned short*)smemA;

  // ---- stage scaled corr (bf16 [64][256] swizzled) from pk registers
  {
    const int pr = tid >> 5, px = tid & 31, p0 = pr*8;
    #pragma unroll
    for (int i=0;i<8;++i){
      const int p = p0 + i;
      uint2 g1; g1.x = pk[i][0]; g1.y = pk[i][1];
      uint2 g2; g2.x = pk[i][2]; g2.y = pk[i][3];
      *(uint2*)&sA16[swz(p, px*4)]       = g1;
      *(uint2*)&sA16[swz(p, 128 + px*4)] = g2;
    }
  }
  __syncthreads();

  // ---- depthwise 3x3 (pad 1) -> d_T [256 pix][64 p] bf16 swizzled (smemB)
  {
    const int p = lane;                      // wave handles rows 4w..4w+3
    float wd[9];
    #pragma unroll
    for (int k=0;k<9;++k) wd[k] = dw[p*9+k];
    #pragma unroll
    for (int io=0;io<4;++io){
      const int ir = wave*4 + io;
      float r0[16], r1[16], r2[16];
      load_row16(sA16, p, ir-1, r0);
      load_row16(sA16, p, ir,   r1);
      load_row16(sA16, p, ir+1, r2);
      #pragma unroll
      for (int j=0;j<16;++j){
        float s = 0.f;
        #pragma unroll
        for (int dj=0;dj<3;++dj){
          const int jj = j-1+dj;
          if (jj>=0 && jj<16){
            s = fmaf(wd[0*3+dj], r0[jj], s);
            s = fmaf(wd[1*3+dj], r1[jj], s);
            s = fmaf(wd[2*3+dj], r2[jj], s);
          }
        }
        // lanes = p, fixed pix per store -> 64 contiguous b16: conflict-free
        *(unsigned short*)(smemB + dT_off(ir*16+j, p)) = f2bf(s);
      }
    }
  }
  __syncthreads();   // corr A free; d_T complete

  // ---- BN scale/bias table + stage chunk-0 weights
  float* scl = (float*)(smemA + 29184);      // 256 f32
  float* bia = scl + 256;                    // 256 f32
  {
    const float s = bng[tid] * rsqrtf(bnv[tid] + 1e-5f);
    scl[tid] = s;
    bia[tid] = bnb[tid] - bnm[tid]*s;
  }
  stage_pw(tid, 0, pw, smemA + 16384);
  stage_wA<NOUT>(tid, 0, pdw, smemA + 24576);

  // pred accumulators: lane<16 reg r holds out[o=r][row rt][col=l15]
  f32x4 accp[4];
  #pragma unroll
  for (int nt=0;nt<4;++nt) accp[nt] = f32x4{0.f,0.f,0.f,0.f};

  for (int ch=0; ch<8; ++ch){
    const int buf = ch & 1, oc0 = ch*32;
    __syncthreads();   // staged buf ready; prev pred finished reading feat_T

    // ---- pointwise via MFMA: feat[32 oc][256 pix] = pw(32x64) * d(64x256)
    unsigned char* pAb = smemA + 16384 + buf*4096;
    U8 af[2][2];
    #pragma unroll
    for (int mt=0;mt<2;++mt)
      #pragma unroll
      for (int ks=0;ks<2;++ks)
        af[mt][ks].q = *(const uint4*)(pAb + pA_off(mt*16 + l15, ks*32 + lg*8));
    f32x4 accw[2][4];
    #pragma unroll
    for (int mt=0;mt<2;++mt)
      #pragma unroll
      for (int nt=0;nt<4;++nt) accw[mt][nt] = f32x4{0.f,0.f,0.f,0.f};
    #pragma unroll
    for (int nt=0;nt<4;++nt){
      const int pix = wave*64 + nt*16 + l15;
      U8 b0, b1;
      b0.q = *(const uint4*)(smemB + dT_off(pix, lg*8));
      b1.q = *(const uint4*)(smemB + dT_off(pix, 32 + lg*8));
      #pragma unroll
      for (int mt=0;mt<2;++mt){
        accw[mt][nt] = __builtin_amdgcn_mfma_f32_16x16x32_bf16(
            af[mt][0].v, b0.v, accw[mt][nt], 0, 0, 0);
        accw[mt][nt] = __builtin_amdgcn_mfma_f32_16x16x32_bf16(
            af[mt][1].v, b1.v, accw[mt][nt], 0, 0, 0);
      }
    }
    // BN + ReLU -> feat_T [pix][32 ocl] bf16 (D: row=oc=(lg*4+r), col=pix=l15)
    #pragma unroll
    for (int mt=0;mt<2;++mt){
      #pragma unroll
      for (int r=0;r<4;++r){
        const int ocl = mt*16 + lg*4 + r;
        const float sc = scl[oc0+ocl], bi = bia[oc0+ocl];
        #pragma unroll
        for (int nt=0;nt<4;++nt){
          const int pix = wave*64 + nt*16 + l15;
          const float v = fmaxf(fmaf(accw[mt][nt][r], sc, bi), 0.f);
          *(unsigned short*)(smemA + fT_off(pix, ocl)) = f2bf(v);
        }
      }
    }
    __syncthreads();   // feat_T chunk ready

    // ---- pred 3x3 partial via MFMA: out[o][r][c] += sum_{ocl,tau}
    unsigned char* wAb = smemA + 24576 + buf*2304;
    #pragma unroll
    for (int dr=0;dr<3;++dr){
      #pragma unroll
      for (int dc=0;dc<3;++dc){
        const int tau = dr*3 + dc;
        U8 a;
        const int mr = (NOUT == 4) ? (l15 & 3) : 0;
        a.q = *(const uint4*)(wAb + ((mr*288 + tau*32 + lg*8) << 1));
        if (l15 >= NOUT) a.q = make_uint4(0u,0u,0u,0u);
        #pragma unroll
        for (int nt=0;nt<4;++nt){
          const int rp = wave*4 + nt + dr - 1;      // uniform per wave
          if (rp >= 0 && rp <= 15){
            const int cp = l15 + dc - 1;
            const int cc = cp < 0 ? 0 : (cp > 15 ? 15 : cp);
            U8 bf;
            bf.q = *(const uint4*)(smemA + fT_off(rp*16 + cc, lg*8));
            if (cp != cc) bf.q = make_uint4(0u,0u,0u,0u);
            accp[nt] = __builtin_amdgcn_mfma_f32_16x16x32_bf16(
                a.v, bf.v, accp[nt], 0, 0, 0);
          }
        }
      }
    }
    // stage next chunk's weights (writes buf^1; no reader this phase)
    if (ch < 7){
      stage_pw(tid, oc0 + 32, pw, smemA + 16384 + (buf^1)*4096);
      stage_wA<NOUT>(tid, oc0 + 32, pdw, smemA + 24576 + (buf^1)*2304);
    }
  }

  // ---- epilogue: lanes 0-15 hold rows 0-3 (= output channels) in regs 0-3
  if (lane < 16){
    #pragma unroll
    for (int nt=0;nt<4;++nt){
      const int rt = wave*4 + nt;
      if constexpr (NOUT == 1){
        outp[rt*16 + lane] = 0.1f*(accp[nt][0] + pdb[0]);
      } else {
        #pragma unroll
        for (int o=0;o<4;++o)
          outp[o*256 + rt*16 + lane] =
              expf(fmaf(adj, accp[nt][o] + pdb[o], biasp[o]));
      }
    }
  }
  __syncthreads();   // protect feat_T/smemA before next tower restages corr A
}

__global__ __launch_bounds__(256, 2) void fused_head(
  const float* __restrict__ search, const float* __restrict__ kern,
  const float* __restrict__ ca_w1, const float* __restrict__ ca_b1,
  const float* __restrict__ ca_w2, const float* __restrict__ ca_b2,
  const float* __restrict__ cls_dw, const float* __restrict__ cls_pw,
  const float* __restrict__ cls_bn_g, const float* __restrict__ cls_bn_b,
  const float* __restrict__ cls_bn_m, const float* __restrict__ cls_bn_v,
  const float* __restrict__ cls_pred_w, const float* __restrict__ cls_pred_b,
  const float* __restrict__ box_dw, const float* __restrict__ box_pw,
  const float* __restrict__ box_bn_g, const float* __restrict__ box_bn_b,
  const float* __restrict__ box_bn_m, const float* __restrict__ box_bn_v,
  const float* __restrict__ box_pred_w, const float* __restrict__ box_pred_b,
  const float* __restrict__ adjust, const float* __restrict__ bias_p,
  float* __restrict__ out)
{
  __shared__ __align__(16) unsigned char smemA[32768];
  __shared__ __align__(16) unsigned char smemB[32768];
  const int b   = blockIdx.x;
  const int tid = threadIdx.x;
  const int pr = tid>>5, px = tid&31, p0 = pr*8;

  float acc[8][8];
  #pragma unroll
  for (int i=0;i<8;++i)
    #pragma unroll
    for (int x=0;x<8;++x) acc[i][x]=0.f;

  // ---- corr GEMM: acc[p0+i][pix(px,x)] = sum_c z[c][p]*search[c][pix]
  float* zsf = (float*)smemB;                  // [112][64]
  {
    const float4* kb = (const float4*)(kern + (size_t)b*7168);
    float4* zb = (float4*)zsf;
    #pragma unroll
    for (int k=0;k<7;++k) zb[k*256+tid] = kb[k*256+tid];
  }
  float* ssf = (float*)smemA;                  // [16][256] chunk
  const float* sea = search + (size_t)b*28672;
  for (int chn=0; chn<7; ++chn){
    __syncthreads();
    {
      const float4* sb = (const float4*)(sea + chn*4096);
      float4* db = (float4*)ssf;
      #pragma unroll
      for (int k=0;k<4;++k) db[k*256+tid] = sb[k*256+tid];
    }
    __syncthreads();
    #pragma unroll 2
    for (int cc=0; cc<16; ++cc){
      const int c = chn*16 + cc;
      float4 zA  = *(const float4*)&zsf[c*64 + p0];
      float4 zB  = *(const float4*)&zsf[c*64 + p0 + 4];
      float4 sAv = *(const float4*)&ssf[cc*256 + px*4];
      float4 sBv = *(const float4*)&ssf[cc*256 + 128 + px*4];
      float zz[8] = {zA.x,zA.y,zA.z,zA.w,zB.x,zB.y,zB.z,zB.w};
      float sv[8] = {sAv.x,sAv.y,sAv.z,sAv.w,sBv.x,sBv.y,sBv.z,sBv.w};
      #pragma unroll
      for (int i=0;i<8;++i)
        #pragma unroll
        for (int x=0;x<8;++x)
          acc[i][x] = fmaf(zz[i], sv[x], acc[i][x]);
    }
  }
  __syncthreads();

  // ---- means (unscaled) + channel-attention MLP
  float* smean = (float*)smemA;     // 64
  float* h1    = smean + 64;        // 64
  float* attv  = smean + 128;       // 64
  #pragma unroll
  for (int i=0;i<8;++i){
    float ms = 0.f;
    #pragma unroll
    for (int x=0;x<8;++x) ms += acc[i][x];
    #pragma unroll
    for (int m=1;m<32;m<<=1) ms += __shfl_xor(ms, m, 64);
    if (px==0) smean[p0+i] = ms * (1.f/256.f);
  }
  __syncthreads();
  if (tid < 64){
    float s = ca_b1[tid];
    const float* wr = ca_w1 + tid*64;
    #pragma unroll 8
    for (int k=0;k<64;++k) s += smean[k]*wr[k];
    h1[tid] = fmaxf(s, 0.f);
  }
  __syncthreads();
  if (tid < 64){
    float s = ca_b2[tid];
    const float* wr = ca_w2 + tid*64;
    #pragma unroll 8
    for (int k=0;k<64;++k) s += h1[k]*wr[k];
    attv[tid] = 1.f/(1.f + expf(-s));
  }
  __syncthreads();

  // ---- apply attention and pack to bf16x2 (32 VGPRs); fp32 acc dies here
  unsigned int pk[8][4];
  {
    float am[8];
    #pragma unroll
    for (int i=0;i<8;++i) am[i] = attv[p0+i];
    __syncthreads();                           // attv consumed before reuse
    #pragma unroll
    for (int i=0;i<8;++i){
      #pragma unroll
      for (int x=0;x<4;++x)
        pk[i][x] = f2bf2(acc[i][2*x]*am[i], acc[i][2*x+1]*am[i]);
    }
  }

  const float adj = adjust[0];

  run_tower<1>(tid, pk, cls_dw, cls_pw, cls_bn_g, cls_bn_b, cls_bn_m, cls_bn_v,
               cls_pred_w, cls_pred_b, out + 524288 + (size_t)b*256,
               adj, bias_p, smemA, smemB);
  run_tower<4>(tid, pk, box_dw, box_pw, box_bn_g, box_bn_b, box_bn_m, box_bn_v,
               box_pred_w, box_pred_b, out + (size_t)b*1024,
               adj, bias_p, smemA, smemB);
}

extern "C" void kernel_launch(void* const* d_in, const int* in_sizes, int n_in,
                              void* d_out, int out_size, void* d_ws, size_t ws_size,
                              hipStream_t stream) {
  (void)in_sizes; (void)n_in; (void)d_ws; (void)ws_size; (void)out_size;
  const float* search     = (const float*)d_in[0];
  const float* kern       = (const float*)d_in[1];
  const float* ca_w1      = (const float*)d_in[2];
  const float* ca_b1      = (const float*)d_in[3];
  const float* ca_w2      = (const float*)d_in[4];
  const float* ca_b2      = (const float*)d_in[5];
  const float* cls_dw     = (const float*)d_in[6];
  const float* cls_pw     = (const float*)d_in[7];
  const float* cls_bn_g   = (const float*)d_in[8];
  const float* cls_bn_b   = (const float*)d_in[9];
  const float* cls_bn_m   = (const float*)d_in[10];
  const float* cls_bn_v   = (const float*)d_in[11];
  const float* cls_pred_w = (const float*)d_in[12];
  const float* cls_pred_b = (const float*)d_in[13];
  const float* box_dw     = (const float*)d_in[14];
  const float* box_pw     = (const float*)d_in[15];
  const float* box_bn_g   = (const float*)d_in[16];
  const float* box_bn_b   = (const float*)d_in[17];
  const float* box_bn_m   = (const float*)d_in[18];
  const float* box_bn_v   = (const float*)d_in[19];
  const float* box_pred_w = (const float*)d_in[20];
  const float* box_pred_b = (const float*)d_in[21];
  const float* adjust     = (const float*)d_in[22];
  const float* bias_p     = (const float*)d_in[23];

  hipLaunchKernelGGL(fused_head, dim3(512), dim3(256), 0, stream,
    search, kern, ca_w1, ca_b1, ca_w2, ca_b2,
    cls_dw, cls_pw, cls_bn_g, cls_bn_b, cls_bn_m, cls_bn_v,
    cls_pred_w, cls_pred_b,
    box_dw, box_pw, box_bn_g, box_bn_b, box_bn_m, box_bn_v,
    box_pred_w, box_pred_b, adjust, bias_p,
    (float*)d_out);
}

// Round 2
// 82.999 us; speedup vs baseline: 3.4765x; 1.2345x over previous
//
#include <hip/hip_runtime.h>
#include <hip/hip_bf16.h>

// ---------------------------------------------------------------------------
// Fused SiamCAR head, one block per batch (B=512), Round 4: 512 threads
// (8 waves -> 16 waves/CU, 50% occupancy) and corr GEMM moved to MFMA with
// hi/lo bf16 split on z (kernel) operand for ~fp32 corr accuracy.
// Towers (dw3x3 -> pw MFMA -> BN/ReLU -> 3x3 pred MFMA) re-partitioned to
// 8 waves: wave owns 32 pix (pointwise) / 2 output rows (pred).
// ---------------------------------------------------------------------------

typedef __attribute__((ext_vector_type(8))) short  bf16x8;
typedef __attribute__((ext_vector_type(4))) float  f32x4;

union U8 { bf16x8 v; uint4 q; unsigned short u[8]; };

__device__ __forceinline__ float bf2f(unsigned short h){
  union { unsigned int u; float f; } c; c.u = ((unsigned int)h) << 16; return c.f;
}
__device__ __forceinline__ unsigned short f2bf(float f){
  union { float f; unsigned int u; } c; c.f = f;
  unsigned int r = (c.u + 0x7FFFu + ((c.u >> 16) & 1u)) >> 16;  // RNE
  return (unsigned short)r;
}
__device__ __forceinline__ unsigned int f2bf2(float lo, float hi){
  return (unsigned int)f2bf(lo) | ((unsigned int)f2bf(hi) << 16);
}

// corr A tile [64 p][256 pix] bf16, elem index, 16B-chunk XOR swizzle.
__device__ __forceinline__ int swz(int row, int pix){
  return row*256 + (((pix>>3) ^ (row&31))<<3) + (pix&7);
}
// z^T tile [64 p][128 c] bf16, byte offset (256B rows, 16 chunks XOR by p).
__device__ __forceinline__ int zt_off(int p, int c){
  return (p<<8) + ((((c>>3) ^ (p&15)) & 15)<<4) + ((c&7)<<1);
}
// search^T chunk [256 pix][64 c] bf16, byte offset (128B rows, 8 chunks).
__device__ __forceinline__ int sT_off(int pix, int c){
  return (pix<<7) + ((((c>>3) ^ (pix&7) ^ ((pix>>3)&7)) & 7)<<4) + ((c&7)<<1);
}
// d_T [256 pix][64 p] bf16, byte offset.
__device__ __forceinline__ int dT_off(int pix, int p){
  return (pix<<7) + (((((p>>3) ^ pix) & 7)) << 4) + ((p & 7) << 1);
}
// feat_T [256 pix][32 ocl] bf16, byte offset.
__device__ __forceinline__ int fT_off(int pix, int ocl){
  return (pix<<6) + ((((ocl>>3) ^ pix ^ (pix>>2)) & 3) << 4) + ((ocl & 7) << 1);
}
// pw A-tile [32 ocl][64 p] bf16, byte offset.
__device__ __forceinline__ int pA_off(int ocl, int p){
  return (ocl<<7) + (((((p>>3) ^ ocl) & 7)) << 4) + ((p & 7) << 1);
}

// load one 16-pixel row (bf16, swizzled corr A) -> fp32, zero-padded
__device__ __forceinline__ void load_row16(const unsigned short* s, int p, int r,
                                           float* out){
  if (r >= 0 && r < 16){
    unsigned short tr[16];
    *(uint4*)&tr[0] = *(uint4*)&s[swz(p, r*16)];
    *(uint4*)&tr[8] = *(uint4*)&s[swz(p, r*16 + 8)];
    #pragma unroll
    for (int j=0;j<16;++j) out[j] = bf2f(tr[j]);
  } else {
    #pragma unroll
    for (int j=0;j<16;++j) out[j] = 0.f;
  }
}

// stage one 32-oc chunk of pw (fp32 global) -> [32][64] bf16 swizzled (512 thr)
__device__ __forceinline__ void stage_pw(int tid, int oc0,
                                         const float* __restrict__ pw,
                                         unsigned char* __restrict__ dst){
  const int ocl = tid >> 4, p0 = (tid & 15) << 2;
  const float4 f0 = *(const float4*)&pw[(oc0 + ocl)*64 + p0];
  unsigned int w0 = f2bf2(f0.x, f0.y);
  unsigned int w1 = f2bf2(f0.z, f0.w);
  uint2 w; w.x = w0; w.y = w1;
  *(uint2*)(dst + pA_off(ocl, p0)) = w;
}

// stage pred weights for one oc-chunk: wA[o][k = tau*32 + ocl] bf16 (512 thr)
template<int NOUT>
__device__ __forceinline__ void stage_wA(int tid, int oc0,
                                         const float* __restrict__ pdw,
                                         unsigned char* __restrict__ dst){
  #pragma unroll
  for (int i=0;i<(NOUT*288+511)/512;++i){
    const int idx = i*512 + tid;
    if (idx < NOUT*288){
      const int o   = idx / 288;
      const int rem = idx - o*288;
      const int tau = rem >> 5, ocl = rem & 31;
      *(unsigned short*)(dst + (idx<<1)) =
          f2bf(pdw[(o*256 + oc0 + ocl)*9 + tau]);
    }
  }
}

template<int NOUT>
__device__ __forceinline__ void run_tower(
    int tid, const unsigned int pk[16],
    const float* __restrict__ dw,  const float* __restrict__ pw,
    const float* __restrict__ bng, const float* __restrict__ bnb,
    const float* __restrict__ bnm, const float* __restrict__ bnv,
    const float* __restrict__ pdw, const float* __restrict__ pdb,
    float* __restrict__ outp, float adj, const float* __restrict__ biasp,
    unsigned char* smem)
{
  const int lane = tid & 63, wave = tid >> 6;
  const int l15 = lane & 15, lg = lane >> 4;
  unsigned short* sA16 = (unsigned short*)smem;            // corr A [64][256]

  // ---- stage scaled corr (bf16 swizzled) from pk frags
  // frag layout: p = mt*16 + lg*4 + r, pix = wave*32 + nt*16 + l15
  #pragma unroll
  for (int mt=0;mt<4;++mt){
    #pragma unroll
    for (int nt=0;nt<2;++nt){
      const int pix = wave*32 + nt*16 + l15;
      #pragma unroll
      for (int rp=0;rp<2;++rp){
        const unsigned int v = pk[(mt*2+nt)*2+rp];
        const int p = mt*16 + lg*4 + rp*2;
        sA16[swz(p,   pix)] = (unsigned short)(v & 0xffffu);
        sA16[swz(p+1, pix)] = (unsigned short)(v >> 16);
      }
    }
  }
  __syncthreads();

  // ---- depthwise 3x3 (pad 1) -> d_T [256 pix][64 p] bf16 (smem+32768)
  {
    const int p = lane;                      // wave handles rows 2w..2w+1
    unsigned char* dT = smem + 32768;
    float wd[9];
    #pragma unroll
    for (int k=0;k<9;++k) wd[k] = dw[p*9+k];
    #pragma unroll
    for (int io=0;io<2;++io){
      const int ir = wave*2 + io;
      float r0[16], r1[16], r2[16];
      load_row16(sA16, p, ir-1, r0);
      load_row16(sA16, p, ir,   r1);
      load_row16(sA16, p, ir+1, r2);
      #pragma unroll
      for (int j=0;j<16;++j){
        float s = 0.f;
        #pragma unroll
        for (int dj=0;dj<3;++dj){
          const int jj = j-1+dj;
          if (jj>=0 && jj<16){
            s = fmaf(wd[0*3+dj], r0[jj], s);
            s = fmaf(wd[1*3+dj], r1[jj], s);
            s = fmaf(wd[2*3+dj], r2[jj], s);
          }
        }
        *(unsigned short*)(dT + dT_off(ir*16+j, p)) = f2bf(s);
      }
    }
  }
  __syncthreads();   // corr A free; d_T complete

  // ---- BN scale/bias tables + chunk-0 weight staging
  float* scl = (float*)(smem + 16384);       // 256 f32
  float* bia = (float*)(smem + 17408);       // 256 f32
  if (tid < 256){
    const float s = bng[tid] * rsqrtf(bnv[tid] + 1e-5f);
    scl[tid] = s;
    bia[tid] = bnb[tid] - bnm[tid]*s;
  }
  stage_pw(tid, 0, pw, smem + 18432);
  stage_wA<NOUT>(tid, 0, pdw, smem + 26624);

  // pred accumulators: wave owns image rows 2w..2w+1; lane<16 reg r = out ch
  f32x4 accp[2];
  #pragma unroll
  for (int nt=0;nt<2;++nt) accp[nt] = f32x4{0.f,0.f,0.f,0.f};

  for (int ch=0; ch<8; ++ch){
    const int buf = ch & 1, oc0 = ch*32;
    __syncthreads();   // staged buf ready; prev pred finished reading feat_T

    // ---- pointwise via MFMA: feat[32 oc][256 pix] = pw(32x64) * d(64x256)
    unsigned char* pAb = smem + 18432 + buf*4096;
    unsigned char* dT  = smem + 32768;
    U8 af[2][2];
    #pragma unroll
    for (int mt=0;mt<2;++mt)
      #pragma unroll
      for (int ks=0;ks<2;++ks)
        af[mt][ks].q = *(const uint4*)(pAb + pA_off(mt*16 + l15, ks*32 + lg*8));
    f32x4 accw[2][2];
    #pragma unroll
    for (int mt=0;mt<2;++mt)
      #pragma unroll
      for (int nt=0;nt<2;++nt) accw[mt][nt] = f32x4{0.f,0.f,0.f,0.f};
    #pragma unroll
    for (int nt=0;nt<2;++nt){
      const int pix = wave*32 + nt*16 + l15;
      U8 b0, b1;
      b0.q = *(const uint4*)(dT + dT_off(pix, lg*8));
      b1.q = *(const uint4*)(dT + dT_off(pix, 32 + lg*8));
      #pragma unroll
      for (int mt=0;mt<2;++mt){
        accw[mt][nt] = __builtin_amdgcn_mfma_f32_16x16x32_bf16(
            af[mt][0].v, b0.v, accw[mt][nt], 0, 0, 0);
        accw[mt][nt] = __builtin_amdgcn_mfma_f32_16x16x32_bf16(
            af[mt][1].v, b1.v, accw[mt][nt], 0, 0, 0);
      }
    }
    // BN + ReLU -> feat_T [pix][32 ocl] bf16 (smem+0)
    #pragma unroll
    for (int mt=0;mt<2;++mt){
      #pragma unroll
      for (int r=0;r<4;++r){
        const int ocl = mt*16 + lg*4 + r;
        const float sc = scl[oc0+ocl], bi = bia[oc0+ocl];
        #pragma unroll
        for (int nt=0;nt<2;++nt){
          const int pix = wave*32 + nt*16 + l15;
          const float v = fmaxf(fmaf(accw[mt][nt][r], sc, bi), 0.f);
          *(unsigned short*)(smem + fT_off(pix, ocl)) = f2bf(v);
        }
      }
    }
    __syncthreads();   // feat_T chunk ready

    // ---- pred 3x3 partial via MFMA
    unsigned char* wAb = smem + 26624 + buf*2304;
    #pragma unroll
    for (int dr=0;dr<3;++dr){
      #pragma unroll
      for (int dc=0;dc<3;++dc){
        const int tau = dr*3 + dc;
        U8 a;
        const int mr = (NOUT == 4) ? (l15 & 3) : 0;
        a.q = *(const uint4*)(wAb + ((mr*288 + tau*32 + lg*8) << 1));
        if (l15 >= NOUT) a.q = make_uint4(0u,0u,0u,0u);
        #pragma unroll
        for (int nt=0;nt<2;++nt){
          const int rp = wave*2 + nt + dr - 1;      // uniform per wave
          if (rp >= 0 && rp <= 15){
            const int cp = l15 + dc - 1;
            const int cc = cp < 0 ? 0 : (cp > 15 ? 15 : cp);
            U8 bf;
            bf.q = *(const uint4*)(smem + fT_off(rp*16 + cc, lg*8));
            if (cp != cc) bf.q = make_uint4(0u,0u,0u,0u);
            accp[nt] = __builtin_amdgcn_mfma_f32_16x16x32_bf16(
                a.v, bf.v, accp[nt], 0, 0, 0);
          }
        }
      }
    }
    // stage next chunk's weights (writes buf^1; no reader this phase)
    if (ch < 7){
      stage_pw(tid, oc0 + 32, pw, smem + 18432 + (buf^1)*4096);
      stage_wA<NOUT>(tid, oc0 + 32, pdw, smem + 26624 + (buf^1)*2304);
    }
  }

  // ---- epilogue: lanes 0-15 hold out-chs in regs; wave covers rows 2w..2w+1
  if (lane < 16){
    #pragma unroll
    for (int nt=0;nt<2;++nt){
      const int rt = wave*2 + nt;
      if constexpr (NOUT == 1){
        outp[rt*16 + lane] = 0.1f*(accp[nt][0] + pdb[0]);
      } else {
        #pragma unroll
        for (int o=0;o<4;++o)
          outp[o*256 + rt*16 + lane] =
              expf(fmaf(adj, accp[nt][o] + pdb[o], biasp[o]));
      }
    }
  }
  __syncthreads();   // protect feat_T/weights before next tower restages corrA
}

__global__ __launch_bounds__(512, 4) void fused_head(
  const float* __restrict__ search, const float* __restrict__ kern,
  const float* __restrict__ ca_w1, const float* __restrict__ ca_b1,
  const float* __restrict__ ca_w2, const float* __restrict__ ca_b2,
  const float* __restrict__ cls_dw, const float* __restrict__ cls_pw,
  const float* __restrict__ cls_bn_g, const float* __restrict__ cls_bn_b,
  const float* __restrict__ cls_bn_m, const float* __restrict__ cls_bn_v,
  const float* __restrict__ cls_pred_w, const float* __restrict__ cls_pred_b,
  const float* __restrict__ box_dw, const float* __restrict__ box_pw,
  const float* __restrict__ box_bn_g, const float* __restrict__ box_bn_b,
  const float* __restrict__ box_bn_m, const float* __restrict__ box_bn_v,
  const float* __restrict__ box_pred_w, const float* __restrict__ box_pred_b,
  const float* __restrict__ adjust, const float* __restrict__ bias_p,
  float* __restrict__ out)
{
  __shared__ __align__(16) unsigned char smem[65536];
  const int b   = blockIdx.x;
  const int tid = threadIdx.x;
  const int lane = tid & 63, wave = tid >> 6;
  const int l15 = lane & 15, lg = lane >> 4;

  // ---- stage z^T hi/lo [64 p][128 c] bf16 swizzled (hi/lo split of kernel)
  unsigned char* zhi = smem;               // 16KB
  unsigned char* zlo = smem + 16384;       // 16KB
  {
    const float* kb = kern + (size_t)b*7168;
    #pragma unroll
    for (int i=0;i<14;++i){
      const int idx = i*512 + tid;         // layout [112 c][64 p]
      const int c = idx>>6, p = idx&63;
      const float v = kb[idx];
      const unsigned short h = f2bf(v);
      const unsigned short l = f2bf(v - bf2f(h));
      *(unsigned short*)(zhi + zt_off(p,c)) = h;
      *(unsigned short*)(zlo + zt_off(p,c)) = l;
    }
    #pragma unroll
    for (int i=0;i<2;++i){                 // zero-pad c in [112,128)
      const int idx = i*512 + tid;
      const int p = idx>>4, c = 112 + (idx&15);
      *(unsigned short*)(zhi + zt_off(p,c)) = 0;
      *(unsigned short*)(zlo + zt_off(p,c)) = 0;
    }
  }

  // ---- corr via MFMA: corr[64 p][256 pix] = z^T(64x112) * search(112x256)
  unsigned char* stb = smem + 32768;       // search^T chunk [256][64] bf16
  const float* sea = search + (size_t)b*28672;
  f32x4 acc[4][2];
  #pragma unroll
  for (int mt=0;mt<4;++mt)
    #pragma unroll
    for (int nt=0;nt<2;++nt) acc[mt][nt] = f32x4{0.f,0.f,0.f,0.f};

  for (int kc=0;kc<2;++kc){
    __syncthreads();                       // stb free (or z staging done)
    #pragma unroll
    for (int i=0;i<8;++i){
      const int f4i = i*512 + tid;
      const int cc = f4i>>6, pix0 = (f4i&63)<<2;
      const int c  = kc*64 + cc;
      float4 v;
      if (c < 112) v = *(const float4*)(sea + c*256 + pix0);
      else         v = make_float4(0.f,0.f,0.f,0.f);
      const float vv[4] = {v.x, v.y, v.z, v.w};
      #pragma unroll
      for (int j=0;j<4;++j)
        *(unsigned short*)(stb + sT_off(pix0+j, cc)) = f2bf(vv[j]);
    }
    __syncthreads();                       // chunk staged
    #pragma unroll
    for (int kt=0;kt<2;++kt){
      U8 bh[2];
      #pragma unroll
      for (int nt=0;nt<2;++nt){
        const int pix = wave*32 + nt*16 + l15;
        bh[nt].q = *(const uint4*)(stb + sT_off(pix, kt*32 + lg*8));
      }
      #pragma unroll
      for (int mt=0;mt<4;++mt){
        const int co = kc*64 + kt*32 + lg*8;
        U8 ah, al;
        ah.q = *(const uint4*)(zhi + zt_off(mt*16 + l15, co));
        al.q = *(const uint4*)(zlo + zt_off(mt*16 + l15, co));
        #pragma unroll
        for (int nt=0;nt<2;++nt){
          acc[mt][nt] = __builtin_amdgcn_mfma_f32_16x16x32_bf16(
              ah.v, bh[nt].v, acc[mt][nt], 0, 0, 0);
          acc[mt][nt] = __builtin_amdgcn_mfma_f32_16x16x32_bf16(
              al.v, bh[nt].v, acc[mt][nt], 0, 0, 0);
        }
      }
    }
  }
  __syncthreads();                         // corr reads done; stb reusable

  // ---- means + channel-attention MLP
  float* ws    = (float*)(smem + 32768);          // [8][64]
  float* smean = (float*)(smem + 32768 + 2048);   // 64
  float* h1    = smean + 64;                      // 64
  float* attv  = smean + 128;                     // 64
  #pragma unroll
  for (int mt=0;mt<4;++mt){
    #pragma unroll
    for (int r=0;r<4;++r){
      float s = acc[mt][0][r] + acc[mt][1][r];
      s += __shfl_xor(s, 1, 64);
      s += __shfl_xor(s, 2, 64);
      s += __shfl_xor(s, 4, 64);
      s += __shfl_xor(s, 8, 64);
      if (l15 == 0) ws[wave*64 + mt*16 + lg*4 + r] = s;
    }
  }
  __syncthreads();
  if (tid < 64){
    float m = 0.f;
    #pragma unroll
    for (int w=0;w<8;++w) m += ws[w*64 + tid];
    smean[tid] = m * (1.f/256.f);
  }
  __syncthreads();
  if (tid < 64){
    float s = ca_b1[tid];
    const float* wr = ca_w1 + tid*64;
    #pragma unroll 8
    for (int k=0;k<64;++k) s += smean[k]*wr[k];
    h1[tid] = fmaxf(s, 0.f);
  }
  __syncthreads();
  if (tid < 64){
    float s = ca_b2[tid];
    const float* wr = ca_w2 + tid*64;
    #pragma unroll 8
    for (int k=0;k<64;++k) s += h1[k]*wr[k];
    attv[tid] = 1.f/(1.f + expf(-s));
  }
  __syncthreads();

  // ---- apply attention, pack to bf16 pairs along r (16 uints)
  unsigned int pk[16];
  #pragma unroll
  for (int mt=0;mt<4;++mt){
    #pragma unroll
    for (int rp=0;rp<2;++rp){
      const float a0 = attv[mt*16 + lg*4 + rp*2];
      const float a1 = attv[mt*16 + lg*4 + rp*2 + 1];
      #pragma unroll
      for (int nt=0;nt<2;++nt)
        pk[(mt*2+nt)*2+rp] =
            f2bf2(acc[mt][nt][rp*2]*a0, acc[mt][nt][rp*2+1]*a1);
    }
  }
  // attv reads above precede the towers' first barrier -> safe vs d_T reuse

  const float adj = adjust[0];

  run_tower<1>(tid, pk, cls_dw, cls_pw, cls_bn_g, cls_bn_b, cls_bn_m, cls_bn_v,
               cls_pred_w, cls_pred_b, out + 524288 + (size_t)b*256,
               adj, bias_p, smem);
  run_tower<4>(tid, pk, box_dw, box_pw, box_bn_g, box_bn_b, box_bn_m, box_bn_v,
               box_pred_w, box_pred_b, out + (size_t)b*1024,
               adj, bias_p, smem);
}

extern "C" void kernel_launch(void* const* d_in, const int* in_sizes, int n_in,
                              void* d_out, int out_size, void* d_ws, size_t ws_size,
                              hipStream_t stream) {
  (void)in_sizes; (void)n_in; (void)d_ws; (void)ws_size; (void)out_size;
  const float* search     = (const float*)d_in[0];
  const float* kern       = (const float*)d_in[1];
  const float* ca_w1      = (const float*)d_in[2];
  const float* ca_b1      = (const float*)d_in[3];
  const float* ca_w2      = (const float*)d_in[4];
  const float* ca_b2      = (const float*)d_in[5];
  const float* cls_dw     = (const float*)d_in[6];
  const float* cls_pw     = (const float*)d_in[7];
  const float* cls_bn_g   = (const float*)d_in[8];
  const float* cls_bn_b   = (const float*)d_in[9];
  const float* cls_bn_m   = (const float*)d_in[10];
  const float* cls_bn_v   = (const float*)d_in[11];
  const float* cls_pred_w = (const float*)d_in[12];
  const float* cls_pred_b = (const float*)d_in[13];
  const float* box_dw     = (const float*)d_in[14];
  const float* box_pw     = (const float*)d_in[15];
  const float* box_bn_g   = (const float*)d_in[16];
  const float* box_bn_b   = (const float*)d_in[17];
  const float* box_bn_m   = (const float*)d_in[18];
  const float* box_bn_v   = (const float*)d_in[19];
  const float* box_pred_w = (const float*)d_in[20];
  const float* box_pred_b = (const float*)d_in[21];
  const float* adjust     = (const float*)d_in[22];
  const float* bias_p     = (const float*)d_in[23];

  hipLaunchKernelGGL(fused_head, dim3(512), dim3(512), 0, stream,
    search, kern, ca_w1, ca_b1, ca_w2, ca_b2,
    cls_dw, cls_pw, cls_bn_g, cls_bn_b, cls_bn_m, cls_bn_v,
    cls_pred_w, cls_pred_b,
    box_dw, box_pw, box_bn_g, box_bn_b, box_bn_m, box_bn_v,
    box_pred_w, box_pred_b, adjust, bias_p,
    (float*)d_out);
}